// Round 2
// baseline (963.232 us; speedup 1.0000x reference)
//
#include <hip/hip_runtime.h>

// MSDNet fused pipeline on gfx950 — round 2: depth-PAIR fusion.
// d_ws holds 31 zero-halo-padded fp32 planes per batch:
//   subplane (c*NB + b), each HP x WP, interior at [HALO..HALO+511].
// Pair kernel <I> computes depths I and I+1 in one pass:
//   phase A: h_I on a D1-extended 64x64 tile -> LDS (input planes read at dil D0)
//   phase B: h_{I+1} on the tile (same input planes at dil D1 + LDS h_I taps)
// Input planes are thus fetched once per PAIR instead of once per depth.
// Last pair (I=28) fuses the 1x1 conv + output affine and skips h28/h29 writes.

#define MSD_DEPTH 30
#define NB 4
#define IH 512
#define IW 512
#define HALO 12
#define WP (IW + 2 * HALO) /* 536 */
#define HP (IH + 2 * HALO) /* 536 */
#define PLANE ((size_t)WP * (size_t)HP)
#define CSTRIDE ((size_t)NB * PLANE)
#define NPIX (NB * IH * IW)

// ---------------------------------------------------------------------------
__global__ __launch_bounds__(256) void zero_halo_kernel(float* __restrict__ ws) {
    const int per = WP * HP - IW * IH; // 25152
    long idx = (long)blockIdx.x * 256 + threadIdx.x;
    const long total = (long)per * (MSD_DEPTH + 1) * NB;
    if (idx >= total) return;
    int sub = (int)(idx / per);
    int rem = (int)(idx % per);
    int r, c;
    if (rem < HALO * WP) {
        r = rem / WP; c = rem % WP;
    } else if (rem < 2 * HALO * WP) {
        int t = rem - HALO * WP;
        r = (IH + HALO) + t / WP; c = t % WP;
    } else {
        int t = rem - 2 * HALO * WP;
        r = HALO + t / (2 * HALO);
        int u = t % (2 * HALO);
        c = (u < HALO) ? u : (IW + u);
    }
    ws[(size_t)sub * PLANE + (size_t)r * WP + c] = 0.0f;
}

// ---------------------------------------------------------------------------
__global__ __launch_bounds__(256) void scale_in_kernel(const float* __restrict__ x,
                                                       float* __restrict__ ws,
                                                       const float* __restrict__ sw,
                                                       const float* __restrict__ sb) {
    int idx = blockIdx.x * 256 + threadIdx.x;
    int w = idx & (IW - 1);
    int t = idx >> 9;
    int h = t & (IH - 1);
    int b = t >> 9;
    float v = x[idx] * sw[0] + sb[0];
    ws[(size_t)b * PLANE + (size_t)(h + HALO) * WP + (w + HALO)] = v;
}

// ---------------------------------------------------------------------------
template <int I>
__global__ __launch_bounds__(1024) void pair_kernel(float* __restrict__ ws,
                                                    const float* __restrict__ Wmsd,
                                                    const float* __restrict__ bias,
                                                    const float* __restrict__ convW,
                                                    const float* __restrict__ convB,
                                                    const float* __restrict__ soutw,
                                                    const float* __restrict__ soutb,
                                                    float* __restrict__ out) {
    constexpr int D0 = (I % 10) + 1;
    constexpr int D1 = ((I + 1) % 10) + 1;
    constexpr int NC = I + 1;              // input planes for depth I (feats 0..I)
    constexpr bool LAST = (I == MSD_DEPTH - 2);
    constexpr int T = 64;
    constexpr int EW = T + 2 * D1;         // extended tile width for h_I
    constexpr int ES = EW * EW;
    constexpr int NA = (ES + 1023) / 1024; // ext pixels per thread

    __shared__ float h_lds[ES];

    const int tid = threadIdx.x;
    const int bid = blockIdx.x;
    // XCD-band swizzle: bid%8 -> XCD (heuristic); each XCD gets a contiguous
    // 4-tile-row band of one image so vertical tap rows stay in its 4MB L2.
    const int xcd = bid & 7;
    const int kk = bid >> 3;               // 0..31
    const int b = xcd >> 1;                // 2 XCDs per image
    const int ty = (xcd & 1) * 4 + (kk >> 3);
    const int tx = kk & 7;
    const int gx0 = tx * T, gy0 = ty * T;

    const float* wsb = ws + (size_t)b * PLANE;
    const int safe_off = (gy0 + 32 + HALO) * WP + (gx0 + 32 + HALO);

    // Phase-A extended-pixel offsets (+ validity: outside-image h is 0)
    int off0[NA];
    unsigned valmask = 0;
    float acc0[NA];
#pragma unroll
    for (int k = 0; k < NA; ++k) {
        acc0[k] = 0.f;
        int e = tid + k * 1024;
        int ey = e / EW, ex = e - ey * EW;
        int gy = gy0 - D1 + ey, gx = gx0 - D1 + ex;
        bool val = (e < ES) && (gy >= 0) && (gy < IH) && (gx >= 0) && (gx < IW);
        off0[k] = val ? ((gy + HALO) * WP + gx + HALO) : safe_off;
        if (val) valmask |= (1u << k);
    }

    // Phase-B interior pixels (4 per thread)
    int offB[4];
    float acc1[4];
    float ydot[4];
#pragma unroll
    for (int j = 0; j < 4; ++j) {
        int p = tid + j * 1024;
        int iy = p >> 6, ix = p & 63;
        offB[j] = (gy0 + iy + HALO) * WP + (gx0 + ix + HALO);
        acc1[j] = 0.f;
        ydot[j] = 0.f;
    }

    // Single pass over input planes: accumulate both depths' contributions.
    for (int c = 0; c < NC; ++c) {
        const float* pb = wsb + (size_t)c * CSTRIDE;
        const float* w0 = Wmsd + (size_t)I * (MSD_DEPTH * 9) + c * 9;
        const float* w1 = Wmsd + (size_t)(I + 1) * (MSD_DEPTH * 9) + c * 9;
        float cw = LAST ? convW[c] : 0.f;
#pragma unroll
        for (int k = 0; k < NA; ++k) {
            const float* p = pb + off0[k];
            acc0[k] += w0[0] * p[-D0 * WP - D0] + w0[1] * p[-D0 * WP] + w0[2] * p[-D0 * WP + D0]
                     + w0[3] * p[-D0]           + w0[4] * p[0]        + w0[5] * p[D0]
                     + w0[6] * p[D0 * WP - D0]  + w0[7] * p[D0 * WP]  + w0[8] * p[D0 * WP + D0];
        }
#pragma unroll
        for (int j = 0; j < 4; ++j) {
            const float* p = pb + offB[j];
            float ctr = p[0];
            acc1[j] += w1[0] * p[-D1 * WP - D1] + w1[1] * p[-D1 * WP] + w1[2] * p[-D1 * WP + D1]
                     + w1[3] * p[-D1]           + w1[4] * ctr         + w1[5] * p[D1]
                     + w1[6] * p[D1 * WP - D1]  + w1[7] * p[D1 * WP]  + w1[8] * p[D1 * WP + D1];
            if (LAST) ydot[j] += cw * ctr;
        }
    }

    // Finalize h_I into LDS (zero outside image = zero-padding semantics).
    const float b0 = bias[I];
#pragma unroll
    for (int k = 0; k < NA; ++k) {
        int e = tid + k * 1024;
        float h = acc0[k] + b0;
        h = h > 0.f ? h : 0.f;
        if (!(valmask & (1u << k))) h = 0.f;
        if (e < ES) h_lds[e] = h;
    }
    __syncthreads();

    // Phase B finish: add h_I taps from LDS, write results.
    const float* w1h = Wmsd + (size_t)(I + 1) * (MSD_DEPTH * 9) + (I + 1) * 9;
    const float b1 = bias[I + 1];
    float* wsI1 = ws + (size_t)((NC) * NB + b) * PLANE;      // plane I+1 (h_I)
    float* wsI2 = ws + (size_t)((NC + 1) * NB + b) * PLANE;  // plane I+2 (h_{I+1})
#pragma unroll
    for (int j = 0; j < 4; ++j) {
        int p_ = tid + j * 1024;
        int iy = p_ >> 6, ix = p_ & 63;
        const float* hp = h_lds + (iy + D1) * EW + (ix + D1);
        float hc = hp[0];
        float a = acc1[j]
                + w1h[0] * hp[-D1 * EW - D1] + w1h[1] * hp[-D1 * EW] + w1h[2] * hp[-D1 * EW + D1]
                + w1h[3] * hp[-D1]           + w1h[4] * hc           + w1h[5] * hp[D1]
                + w1h[6] * hp[D1 * EW - D1]  + w1h[7] * hp[D1 * EW]  + w1h[8] * hp[D1 * EW + D1];
        float h1 = a + b1;
        h1 = h1 > 0.f ? h1 : 0.f;
        if (!LAST) {
            wsI1[offB[j]] = hc;
            wsI2[offB[j]] = h1;
        } else {
            float y = ydot[j] + convW[MSD_DEPTH - 1] * hc + convW[MSD_DEPTH] * h1 + convB[0];
            y = y * soutw[0] + soutb[0];
            out[((size_t)b * IH + gy0 + iy) * IW + gx0 + ix] = y;
        }
    }
}

// ---------------------------------------------------------------------------
extern "C" void kernel_launch(void* const* d_in, const int* in_sizes, int n_in,
                              void* d_out, int out_size, void* d_ws, size_t ws_size,
                              hipStream_t stream) {
    const float* x     = (const float*)d_in[0];
    const float* Wmsd  = (const float*)d_in[1];
    const float* bias  = (const float*)d_in[2];
    const float* convW = (const float*)d_in[3];
    const float* convB = (const float*)d_in[4];
    const float* sinw  = (const float*)d_in[5];
    const float* sinb  = (const float*)d_in[6];
    const float* soutw = (const float*)d_in[7];
    const float* soutb = (const float*)d_in[8];
    float* out = (float*)d_out;
    float* ws  = (float*)d_ws;

    const long halo_total = (long)(WP * HP - IW * IH) * (MSD_DEPTH + 1) * NB;
    int zb = (int)((halo_total + 255) / 256);
    zero_halo_kernel<<<zb, 256, 0, stream>>>(ws);

    scale_in_kernel<<<NPIX / 256, 256, 0, stream>>>(x, ws, sinw, sinb);

#define LNCH(I) pair_kernel<I><<<256, 1024, 0, stream>>>(ws, Wmsd, bias, convW, convB, soutw, soutb, out);
    LNCH(0)  LNCH(2)  LNCH(4)  LNCH(6)  LNCH(8)
    LNCH(10) LNCH(12) LNCH(14) LNCH(16) LNCH(18)
    LNCH(20) LNCH(22) LNCH(24) LNCH(26) LNCH(28)
#undef LNCH
}